// Round 7
// baseline (232.292 us; speedup 1.0000x reference)
//
#include <hip/hip_runtime.h>
#include <math.h>

#define B_ 16
#define S_ 512
#define D_ 768
#define H_ 12
#define DH_ 64
#define BH_ (B_*H_)     // 192
#define MTOT (B_*S_)    // 8192
#define NTOT (3*D_)     // 2304

typedef unsigned short ushort_t;
typedef __attribute__((ext_vector_type(8))) _Float16 f16x8;
typedef __attribute__((ext_vector_type(4))) float f32x4;

__device__ __forceinline__ ushort_t f2h(float x){
    union { _Float16 h; ushort_t u; } c;
    c.h = (_Float16)x;              // v_cvt_f16_f32, RNE
    return c.u;
}

__device__ __forceinline__ void cp16(const void* g, void* l){
    __builtin_amdgcn_global_load_lds(
        (const __attribute__((address_space(1))) unsigned int*)g,
        (__attribute__((address_space(3))) unsigned int*)l, 16, 0, 0);
}

// ---------------------------------------------------------------------------
// f32 -> f16 (RNE), 4 elems/thread
// ---------------------------------------------------------------------------
__global__ __launch_bounds__(256)
void convert_x(const float* __restrict__ src, ushort_t* __restrict__ dst, int n4)
{
    int i = blockIdx.x * 256 + threadIdx.x;
    if (i >= n4) return;
    float4 x = ((const float4*)src)[i];
    union { ushort_t u[4]; uint2 v; } p;
    p.u[0] = f2h(x.x); p.u[1] = f2h(x.y);
    p.u[2] = f2h(x.z); p.u[3] = f2h(x.w);
    ((uint2*)dst)[i] = p.v;
}

// weights: all three matrices -> one f16 array
__global__ __launch_bounds__(256)
void convert_w(const float* __restrict__ Wq, const float* __restrict__ Wk,
               const float* __restrict__ Wv, ushort_t* __restrict__ dst)
{
    const float* src = (blockIdx.z==0) ? Wq : (blockIdx.z==1) ? Wk : Wv;
    const int n4 = D_*D_/4;
    int i = blockIdx.x * 256 + threadIdx.x;
    if (i >= n4) return;
    size_t off4 = (size_t)blockIdx.z * n4;
    float4 x = ((const float4*)src)[i];
    union { ushort_t u[4]; uint2 v; } p;
    p.u[0] = f2h(x.x); p.u[1] = f2h(x.y);
    p.u[2] = f2h(x.z); p.u[3] = f2h(x.w);
    ((uint2*)dst)[off4 + i] = p.v;
}

// ---------------------------------------------------------------------------
// MFMA GEMM (fp16 single-pass), unchanged from r6.
// mat 0 -> Q f16, 1 -> K f16, 2 -> V f32 [bh][s][d].
// ---------------------------------------------------------------------------
#define BM 128
#define BN 128
#define BK 32

__global__ __launch_bounds__(256)
void gemm_f16(const ushort_t* __restrict__ A, const ushort_t* __restrict__ Bw,
              const float* __restrict__ bq, const float* __restrict__ bk,
              const float* __restrict__ bv,
              ushort_t* __restrict__ qf, ushort_t* __restrict__ kf,
              float* __restrict__ outv)
{
    __shared__ ushort_t Ah[BM*BK], Bh[BN*BK];  // 16 KB

    const int tid  = threadIdx.x;
    const int lane = tid & 63, wave = tid >> 6;

    // XCD swizzle: flat id over (18 x 64) grid, x-fastest
    const int n = blockIdx.y * 18 + blockIdx.x;
    const int nn = (n & 7) * 144 + (n >> 3);
    const int bx = nn % 18, by = nn / 18;
    const int m0 = by * BM, n0 = bx * BN;
    const int wm = (wave >> 1) * 64, wn = (wave & 1) * 64;

    f32x4 acc[4][4];
    #pragma unroll
    for (int i=0;i<4;i++)
        #pragma unroll
        for (int j=0;j<4;j++) acc[i][j] = (f32x4){0.f,0.f,0.f,0.f};

    const int r0 = tid >> 2, c0 = (tid & 3) * 8;
    const size_t ga0 = (size_t)(m0 + r0)      * D_ + c0;
    const size_t ga1 = (size_t)(m0 + 64 + r0) * D_ + c0;
    const size_t gb0 = (size_t)(n0 + r0)      * D_ + c0;
    const size_t gb1 = (size_t)(n0 + 64 + r0) * D_ + c0;
    const int l0 = wave * 512;
    const int l1 = 2048 + wave * 512;

    const int fr = lane & 15, kc = (lane >> 4) * 8;

    for (int k0 = 0; k0 < D_; k0 += BK) {
        cp16(A  + ga0 + k0, Ah + l0);
        cp16(A  + ga1 + k0, Ah + l1);
        cp16(Bw + gb0 + k0, Bh + l0);
        cp16(Bw + gb1 + k0, Bh + l1);
        __syncthreads();

        f16x8 fa[4], fb[4];
        #pragma unroll
        for (int i = 0; i < 4; i++){
            fa[i] = *(const f16x8*)&Ah[(wm + i*16 + fr)*BK + kc];
            fb[i] = *(const f16x8*)&Bh[(wn + i*16 + fr)*BK + kc];
        }
        #pragma unroll
        for (int i = 0; i < 4; i++)
            #pragma unroll
            for (int j = 0; j < 4; j++)
                acc[i][j] = __builtin_amdgcn_mfma_f32_16x16x32_f16(fa[i], fb[j], acc[i][j], 0,0,0);
        __syncthreads();
    }

    const int mat = n0 / D_;   // block-uniform
    const float* bias = (mat==0) ? bq : (mat==1) ? bk : bv;
    const int col = lane & 15, rbase = (lane >> 4) * 4;
    #pragma unroll
    for (int j = 0; j < 4; j++){
        int nc = n0 + wn + j*16 + col - mat*D_;
        int h = nc >> 6, d = nc & 63;
        float bsv = bias[nc];
        #pragma unroll
        for (int i = 0; i < 4; i++){
            #pragma unroll
            for (int r = 0; r < 4; r++){
                int m = m0 + wm + i*16 + rbase + r;
                int bb = m >> 9, s = m & 511;
                size_t idx = (((size_t)bb*H_ + h)*S_ + s)*DH_ + d;
                float val = acc[i][j][r] + bsv;
                if (mat == 2) outv[idx] = val;
                else if (mat == 0) qf[idx] = f2h(val);
                else               kf[idx] = f2h(val);
            }
        }
    }
}

// ---------------------------------------------------------------------------
// MFMA sparsemax attention (fp16 QK^T) + CANDIDATE PRE-FILTERING.
// Sparsemax bound: tau_final >= rowmax - 1, so support subset of
// {z > rowmax-1} (~4-8 of 512 keys for N(0,1) scores). One scan compacts
// each row's candidates (val,key) into a tiny LDS list (per-lane count +
// LDS atomicAdd base; lists are wave-private -> no barrier). Michelot then
// runs on <=4 regs/lane (vs 32) and PV walks the list with 4 V-loads in
// flight. Capacity 64/row; wave-uniform fallback to full-scan path if
// exceeded (adversarial inputs only). Michelot math exactly equivalent:
// every iterate tau_n >= mx-1 already excludes non-candidates.
// ---------------------------------------------------------------------------
#define SROW 320   // f32 per row: 16 owners x 20 (16 keys + 4 pad)
#define LCAP 64

__global__ __launch_bounds__(256)
void attn_mfma(const ushort_t* __restrict__ Qf, const ushort_t* __restrict__ Kf,
               const float* __restrict__ V, const float* __restrict__ mask,
               float* __restrict__ out)
{
    __shared__ float sc[16*SROW];   // 20,480 B; reused for candidate lists
    __shared__ int Lcnt[16];

    const int lane = threadIdx.x & 63;
    const int wave = threadIdx.x >> 6;         // 0..3
    const int fr = lane & 15, quad = lane >> 4;

    if (threadIdx.x < 16) Lcnt[threadIdx.x] = 0;   // ordered by exchange barriers

    // XCD-bijective swizzle: 6144 blocks, 768 per XCD => 24 whole heads/XCD
    const int orig = blockIdx.x;
    const int swz  = (orig & 7) * (BH_*32/8) + (orig >> 3);
    const int bh = swz >> 5;
    const int q0 = (swz & 31) * 16;
    const int b = bh / H_, h = bh % H_;
    const size_t hb = (size_t)bh * S_ * DH_;

    // ---- Phase 1: QK^T scores (fp16, 2 MFMAs per 16-key tile) -------------
    f16x8 qh[2];
    {
        const ushort_t* qp = Qf + hb + (size_t)(q0 + fr)*DH_ + quad*8;
        qh[0] = *(const f16x8*)qp;
        qh[1] = *(const f16x8*)(qp + 32);
    }

    f32x4 acc2[2][4];
    #pragma unroll
    for (int h2=0;h2<2;h2++)
        #pragma unroll
        for (int jj=0;jj<4;jj++) acc2[h2][jj] = (f32x4){0.f,0.f,0.f,0.f};

    __builtin_amdgcn_s_setprio(1);
    #pragma unroll
    for (int h2=0;h2<2;h2++){
        #pragma unroll
        for (int jj=0;jj<4;jj++){
            int kt = h2*256 + wave*64 + jj*16;
            const ushort_t* kp = Kf + hb + (size_t)(kt + fr)*DH_ + quad*8;
            f16x8 k0 = *(const f16x8*)kp;
            f16x8 k1 = *(const f16x8*)(kp + 32);
            f32x4 a = acc2[h2][jj];
            a = __builtin_amdgcn_mfma_f32_16x16x32_f16(qh[0], k0, a, 0,0,0);
            a = __builtin_amdgcn_mfma_f32_16x16x32_f16(qh[1], k1, a, 0,0,0);
            acc2[h2][jj] = a;
        }
    }
    __builtin_amdgcn_s_setprio(0);

    // ---- Half-exchange: scatter half0, read z[0..16), scatter half1, read
    const float* mrow = mask + b * S_;
    const int row = wave*4 + quad;
    float z[32];

    #pragma unroll
    for (int jj=0;jj<4;jj++){
        int k = wave*64 + jj*16 + fr;
        float mv = mrow[k];
        int o = wave*4 + jj;
        #pragma unroll
        for (int r=0;r<4;r++)
            sc[(quad*4+r)*SROW + o*20 + fr] = acc2[0][jj][r]*0.125f + mv;
    }
    __syncthreads();
    {
        const float* zp = &sc[row*SROW + fr*20];
        #pragma unroll
        for (int jj=0;jj<4;jj++){
            float4 t = *(const float4*)(zp + jj*4);
            z[jj*4+0]=t.x; z[jj*4+1]=t.y; z[jj*4+2]=t.z; z[jj*4+3]=t.w;
        }
    }
    __syncthreads();
    #pragma unroll
    for (int jj=0;jj<4;jj++){
        int k = 256 + wave*64 + jj*16 + fr;
        float mv = mrow[k];
        int o = wave*4 + jj;
        #pragma unroll
        for (int r=0;r<4;r++)
            sc[(quad*4+r)*SROW + o*20 + fr] = acc2[1][jj][r]*0.125f + mv;
    }
    __syncthreads();
    {
        const float* zp = &sc[row*SROW + fr*20];
        #pragma unroll
        for (int jj=0;jj<4;jj++){
            float4 t = *(const float4*)(zp + jj*4);
            z[16+jj*4+0]=t.x; z[16+jj*4+1]=t.y; z[16+jj*4+2]=t.z; z[16+jj*4+3]=t.w;
        }
    }
    __syncthreads();   // all exchange reads done; sc reused for lists below

    // ---- Row max: depth-5 tree + 4-step intra-quad butterfly --------------
    float mm;
    {
        float red[16];
        #pragma unroll
        for (int i=0;i<16;i++) red[i] = fmaxf(z[i], z[i+16]);
        #pragma unroll
        for (int i=0;i<8;i++)  red[i] = fmaxf(red[i], red[i+8]);
        #pragma unroll
        for (int i=0;i<4;i++)  red[i] = fmaxf(red[i], red[i+4]);
        mm = fmaxf(fmaxf(red[0],red[1]), fmaxf(red[2],red[3]));
        #pragma unroll
        for (int off=1; off<16; off<<=1) mm = fmaxf(mm, __shfl_xor(mm, off, 64));
    }
    const float tau0 = mm - 1.0f;
    float tau = tau0;

    // ---- Candidate compaction: {z > tau0} -> LDS lists (wave-private) -----
    float* Lval = sc;                    // [16][LCAP]
    int*   Lkey = (int*)(sc + 16*LCAP);  // [16][LCAP]
    {
        int c = 0;
        #pragma unroll
        for (int i=0;i<32;i++) c += (z[i] > tau0) ? 1 : 0;
        int o = atomicAdd(&Lcnt[row], c);
        #pragma unroll
        for (int i=0;i<32;i++){
            if (z[i] > tau0){
                if (o < LCAP){
                    Lval[row*LCAP + o] = z[i];
                    Lkey[row*LCAP + o] = fr*16 + ((i<16) ? i : (240 + i));
                }
                o++;
            }
        }
    }
    const int cnt = Lcnt[row];           // same-wave atomics: final after lgkm wait
    const bool fast = !__any(cnt > LCAP);

    // ---- Michelot fixed-point -------------------------------------------
    if (fast){
        float v0 = (fr      < cnt) ? Lval[row*LCAP + fr     ] : -1e30f;
        float v1 = (fr + 16 < cnt) ? Lval[row*LCAP + fr + 16] : -1e30f;
        float v2 = (fr + 32 < cnt) ? Lval[row*LCAP + fr + 32] : -1e30f;
        float v3 = (fr + 48 < cnt) ? Lval[row*LCAP + fr + 48] : -1e30f;
        for (int it=0; it<16; it++){
            float ss=0.f, kk=0.f;
            if (v0 > tau){ ss+=v0; kk+=1.f; }
            if (v1 > tau){ ss+=v1; kk+=1.f; }
            if (v2 > tau){ ss+=v2; kk+=1.f; }
            if (v3 > tau){ ss+=v3; kk+=1.f; }
            #pragma unroll
            for (int off=1; off<16; off<<=1){
                ss += __shfl_xor(ss, off, 64);
                kk += __shfl_xor(kk, off, 64);
            }
            float tn = (ss - 1.0f) / kk;
            bool changed = (tn != tau);
            tau = tn;
            if (!__any(changed)) break;
        }
    } else {
        for (int it=0; it<16; it++){
            float s0=0.f,s1=0.f,s2=0.f,s3=0.f;
            float k0=0.f,k1=0.f,k2=0.f,k3=0.f;
            #pragma unroll
            for (int i=0;i<32;i+=4){
                float z0=z[i], z1=z[i+1], z2=z[i+2], z3=z[i+3];
                if (z0 > tau){ s0 += z0; k0 += 1.f; }
                if (z1 > tau){ s1 += z1; k1 += 1.f; }
                if (z2 > tau){ s2 += z2; k2 += 1.f; }
                if (z3 > tau){ s3 += z3; k3 += 1.f; }
            }
            float ss = (s0+s1)+(s2+s3), kk = (k0+k1)+(k2+k3);
            #pragma unroll
            for (int off=1; off<16; off<<=1){
                ss += __shfl_xor(ss, off, 64);
                kk += __shfl_xor(kk, off, 64);
            }
            float tn = (ss - 1.0f) / kk;
            bool changed = (tn != tau);
            tau = tn;
            if (!__any(changed)) break;
        }
    }

    // ---- Sparse PV ------------------------------------------------------
    float4 ctx = make_float4(0.f, 0.f, 0.f, 0.f);
    const float* vb = V + hb;
    if (fast){
        // list walk, 4 V-row loads in flight per chunk
        for (int j0 = 0; j0 < cnt; j0 += 4){
            float p[4]; float4 vv[4];
            #pragma unroll
            for (int u=0; u<4; ++u){
                int j = j0 + u;
                bool in = j < cnt;
                float val = in ? Lval[row*LCAP + j] : 0.f;
                int   key = in ? Lkey[row*LCAP + j] : 0;
                float pp = val - tau;
                p[u] = (in && pp > 0.f) ? pp : 0.f;
                vv[u] = *(const float4*)(vb + (size_t)key*DH_ + fr*4);
            }
            #pragma unroll
            for (int u=0; u<4; ++u){
                ctx.x += p[u]*vv[u].x;
                ctx.y += p[u]*vv[u].y;
                ctx.z += p[u]*vv[u].z;
                ctx.w += p[u]*vv[u].w;
            }
        }
    } else {
        // fallback: per-quad ballot walk over full z
        #pragma unroll
        for (int i=0;i<32;i++){
            float p = z[i] - tau;
            unsigned long long bal = __ballot(p > 0.f);
            unsigned mk = (unsigned)((bal >> (quad*16)) & 0xFFFFull);
            const int base_i = (i < 16) ? i : (240 + i);
            while (mk){
                int s = __ffs(mk) - 1;
                mk &= mk - 1;
                float pv = __shfl(p, quad*16 + s, 64);
                const float4 vv = *(const float4*)(vb + (size_t)(base_i + s*16)*DH_ + fr*4);
                ctx.x += pv * vv.x;
                ctx.y += pv * vv.y;
                ctx.z += pv * vv.z;
                ctx.w += pv * vv.w;
            }
        }
    }

    *(float4*)(out + (size_t)(b*S_ + q0 + row)*D_ + h*DH_ + fr*4) = ctx;
}

// ---------------------------------------------------------------------------
extern "C" void kernel_launch(void* const* d_in, const int* in_sizes, int n_in,
                              void* d_out, int out_size, void* d_ws, size_t ws_size,
                              hipStream_t stream) {
    const float* hs   = (const float*)d_in[0];
    const float* mask = (const float*)d_in[1];
    const float* Wq   = (const float*)d_in[2];
    const float* bq   = (const float*)d_in[3];
    const float* Wk   = (const float*)d_in[4];
    const float* bk   = (const float*)d_in[5];
    const float* Wv   = (const float*)d_in[6];
    const float* bv   = (const float*)d_in[7];
    float* out = (float*)d_out;

    const size_t per = (size_t)BH_ * S_ * DH_;   // 6291456
    char* w = (char*)d_ws;
    float*    vb  = (float*)w;    w += per*4;
    ushort_t* qf  = (ushort_t*)w; w += per*2;
    ushort_t* kf  = (ushort_t*)w; w += per*2;
    ushort_t* Xf  = (ushort_t*)w; w += per*2;
    ushort_t* Wf  = (ushort_t*)w;

    convert_x<<<(int)(per/4/256), 256, 0, stream>>>(hs, Xf, (int)(per/4));
    convert_w<<<dim3(D_*D_/4/256, 1, 3), 256, 0, stream>>>(Wq, Wk, Wv, Wf);

    dim3 ggrid(NTOT/BN, MTOT/BM);   // (18, 64)
    gemm_f16<<<ggrid, 256, 0, stream>>>(Xf, Wf, bq, bk, bv, qf, kf, vb);

    attn_mfma<<<BH_*32, 256, 0, stream>>>(qf, kf, vb, mask, out);
}

// Round 9
// 229.919 us; speedup vs baseline: 1.0103x; 1.0103x over previous
//
#include <hip/hip_runtime.h>
#include <math.h>

#define B_ 16
#define S_ 512
#define D_ 768
#define H_ 12
#define DH_ 64
#define BH_ (B_*H_)     // 192
#define MTOT (B_*S_)    // 8192
#define NTOT (3*D_)     // 2304

typedef unsigned short ushort_t;
typedef __attribute__((ext_vector_type(8))) _Float16 f16x8;
typedef __attribute__((ext_vector_type(4))) float f32x4;

__device__ __forceinline__ ushort_t f2h(float x){
    union { _Float16 h; ushort_t u; } c;
    c.h = (_Float16)x;              // v_cvt_f16_f32, RNE
    return c.u;
}

__device__ __forceinline__ void cp16(const void* g, void* l){
    __builtin_amdgcn_global_load_lds(
        (const __attribute__((address_space(1))) unsigned int*)g,
        (__attribute__((address_space(3))) unsigned int*)l, 16, 0, 0);
}

// ---------------------------------------------------------------------------
// Merged f32 -> f16 conversion: X (hidden_states) and Wq/Wk/Wv in ONE launch.
// Bit-identical to the r6 convert_x + convert_w pair (same f2h, same dests);
// both region boundaries are exactly 256-thread-block aligned.
// ---------------------------------------------------------------------------
#define NX4 (B_*S_*D_/4)      // 1,572,864 float4 groups for X (6144 blocks)
#define NW4 (D_*D_/4)         //   147,456 per weight matrix    (576 blocks)

__global__ __launch_bounds__(256)
void convert_all(const float* __restrict__ hs,
                 const float* __restrict__ Wq, const float* __restrict__ Wk,
                 const float* __restrict__ Wv,
                 ushort_t* __restrict__ Xf, ushort_t* __restrict__ Wf)
{
    int i = blockIdx.x * 256 + threadIdx.x;
    const float* src; ushort_t* dst; int idx;
    if (i < NX4){ src = hs; dst = Xf; idx = i; }
    else {
        int j = i - NX4;                   // 0 .. 3*NW4-1
        int m = j / NW4; idx = j - m*NW4;
        src = (m==0) ? Wq : (m==1) ? Wk : Wv;
        dst = Wf + (size_t)m * (D_*D_);
    }
    float4 x = ((const float4*)src)[idx];
    union { ushort_t u[4]; uint2 v; } p;
    p.u[0] = f2h(x.x); p.u[1] = f2h(x.y);
    p.u[2] = f2h(x.z); p.u[3] = f2h(x.w);
    ((uint2*)dst)[idx] = p.v;
}

// ---------------------------------------------------------------------------
// MFMA GEMM (fp16 single-pass): C[m,n] = sum_k X[m,k]*W[n,k] + bias.
// mat 0 -> Q f16, 1 -> K f16, 2 -> V f32 [bh][s][d] (walk PV).
// (r8's V-f16 REVERTED: measured error grew 5x beyond the f16 error model and
// post-timing diverged -> not understood -> reverted per rigor discipline.)
// XCD-bijective block swizzle: 1152 blocks = 8 x 144.
// ---------------------------------------------------------------------------
#define BM 128
#define BN 128
#define BK 32

__global__ __launch_bounds__(256)
void gemm_f16(const ushort_t* __restrict__ A, const ushort_t* __restrict__ Bw,
              const float* __restrict__ bq, const float* __restrict__ bk,
              const float* __restrict__ bv,
              ushort_t* __restrict__ qf, ushort_t* __restrict__ kf,
              float* __restrict__ outv)
{
    __shared__ ushort_t Ah[BM*BK], Bh[BN*BK];  // 16 KB

    const int tid  = threadIdx.x;
    const int lane = tid & 63, wave = tid >> 6;

    // XCD swizzle: flat id over (18 x 64) grid, x-fastest
    const int n = blockIdx.y * 18 + blockIdx.x;
    const int nn = (n & 7) * 144 + (n >> 3);
    const int bx = nn % 18, by = nn / 18;
    const int m0 = by * BM, n0 = bx * BN;
    const int wm = (wave >> 1) * 64, wn = (wave & 1) * 64;

    f32x4 acc[4][4];
    #pragma unroll
    for (int i=0;i<4;i++)
        #pragma unroll
        for (int j=0;j<4;j++) acc[i][j] = (f32x4){0.f,0.f,0.f,0.f};

    const int r0 = tid >> 2, c0 = (tid & 3) * 8;
    const size_t ga0 = (size_t)(m0 + r0)      * D_ + c0;
    const size_t ga1 = (size_t)(m0 + 64 + r0) * D_ + c0;
    const size_t gb0 = (size_t)(n0 + r0)      * D_ + c0;
    const size_t gb1 = (size_t)(n0 + 64 + r0) * D_ + c0;
    const int l0 = wave * 512;
    const int l1 = 2048 + wave * 512;

    const int fr = lane & 15, kc = (lane >> 4) * 8;

    for (int k0 = 0; k0 < D_; k0 += BK) {
        cp16(A  + ga0 + k0, Ah + l0);
        cp16(A  + ga1 + k0, Ah + l1);
        cp16(Bw + gb0 + k0, Bh + l0);
        cp16(Bw + gb1 + k0, Bh + l1);
        __syncthreads();

        f16x8 fa[4], fb[4];
        #pragma unroll
        for (int i = 0; i < 4; i++){
            fa[i] = *(const f16x8*)&Ah[(wm + i*16 + fr)*BK + kc];
            fb[i] = *(const f16x8*)&Bh[(wn + i*16 + fr)*BK + kc];
        }
        #pragma unroll
        for (int i = 0; i < 4; i++)
            #pragma unroll
            for (int j = 0; j < 4; j++)
                acc[i][j] = __builtin_amdgcn_mfma_f32_16x16x32_f16(fa[i], fb[j], acc[i][j], 0,0,0);
        __syncthreads();
    }

    const int mat = n0 / D_;   // block-uniform
    const float* bias = (mat==0) ? bq : (mat==1) ? bk : bv;
    const int col = lane & 15, rbase = (lane >> 4) * 4;
    #pragma unroll
    for (int j = 0; j < 4; j++){
        int nc = n0 + wn + j*16 + col - mat*D_;
        int h = nc >> 6, d = nc & 63;
        float bsv = bias[nc];
        #pragma unroll
        for (int i = 0; i < 4; i++){
            #pragma unroll
            for (int r = 0; r < 4; r++){
                int m = m0 + wm + i*16 + rbase + r;
                int bb = m >> 9, s = m & 511;
                size_t idx = (((size_t)bb*H_ + h)*S_ + s)*DH_ + d;
                float val = acc[i][j][r] + bsv;
                if (mat == 2) outv[idx] = val;
                else if (mat == 0) qf[idx] = f2h(val);
                else               kf[idx] = f2h(val);
            }
        }
    }
}

// ---------------------------------------------------------------------------
// MFMA sparsemax attention (fp16 QK^T, f32 V): exact r6 structure/body.
// Low-LDS (20,480 B) two-half score exchange + sparse ballot-walk PV.
// No launch-bounds min-waves (r3/r4: forced GB-scale spills). Lane fr of a
// quad owns keys {fr*16+[0,16)} U {256+fr*16+[0,16)} of its row.
// ---------------------------------------------------------------------------
#define SROW 320   // f32 per row: 16 owners x 20 (16 keys + 4 pad)

__global__ __launch_bounds__(256)
void attn_mfma(const ushort_t* __restrict__ Qf, const ushort_t* __restrict__ Kf,
               const float* __restrict__ V, const float* __restrict__ mask,
               float* __restrict__ out)
{
    __shared__ float sc[16*SROW];   // 20,480 B

    const int lane = threadIdx.x & 63;
    const int wave = threadIdx.x >> 6;         // 0..3
    const int fr = lane & 15, quad = lane >> 4;

    // XCD-bijective swizzle: 6144 blocks, 768 per XCD => 24 whole heads/XCD
    const int orig = blockIdx.x;
    const int swz  = (orig & 7) * (BH_*32/8) + (orig >> 3);
    const int bh = swz >> 5;
    const int q0 = (swz & 31) * 16;
    const int b = bh / H_, h = bh % H_;
    const size_t hb = (size_t)bh * S_ * DH_;

    // ---- Phase 1: QK^T scores (fp16, 2 MFMAs per 16-key tile) -------------
    f16x8 qh[2];
    {
        const ushort_t* qp = Qf + hb + (size_t)(q0 + fr)*DH_ + quad*8;
        qh[0] = *(const f16x8*)qp;
        qh[1] = *(const f16x8*)(qp + 32);
    }

    f32x4 acc2[2][4];
    #pragma unroll
    for (int h2=0;h2<2;h2++)
        #pragma unroll
        for (int jj=0;jj<4;jj++) acc2[h2][jj] = (f32x4){0.f,0.f,0.f,0.f};

    __builtin_amdgcn_s_setprio(1);
    #pragma unroll
    for (int h2=0;h2<2;h2++){
        #pragma unroll
        for (int jj=0;jj<4;jj++){
            int kt = h2*256 + wave*64 + jj*16;
            const ushort_t* kp = Kf + hb + (size_t)(kt + fr)*DH_ + quad*8;
            f16x8 k0 = *(const f16x8*)kp;
            f16x8 k1 = *(const f16x8*)(kp + 32);
            f32x4 a = acc2[h2][jj];
            a = __builtin_amdgcn_mfma_f32_16x16x32_f16(qh[0], k0, a, 0,0,0);
            a = __builtin_amdgcn_mfma_f32_16x16x32_f16(qh[1], k1, a, 0,0,0);
            acc2[h2][jj] = a;
        }
    }
    __builtin_amdgcn_s_setprio(0);

    // ---- Half-exchange: scatter half0, read z[0..16), scatter half1, read
    const float* mrow = mask + b * S_;
    const int row = wave*4 + quad;
    float z[32];

    #pragma unroll
    for (int jj=0;jj<4;jj++){
        int k = wave*64 + jj*16 + fr;
        float mv = mrow[k];
        int o = wave*4 + jj;
        #pragma unroll
        for (int r=0;r<4;r++)
            sc[(quad*4+r)*SROW + o*20 + fr] = acc2[0][jj][r]*0.125f + mv;
    }
    __syncthreads();
    {
        const float* zp = &sc[row*SROW + fr*20];
        #pragma unroll
        for (int jj=0;jj<4;jj++){
            float4 t = *(const float4*)(zp + jj*4);
            z[jj*4+0]=t.x; z[jj*4+1]=t.y; z[jj*4+2]=t.z; z[jj*4+3]=t.w;
        }
    }
    __syncthreads();
    #pragma unroll
    for (int jj=0;jj<4;jj++){
        int k = 256 + wave*64 + jj*16 + fr;
        float mv = mrow[k];
        int o = wave*4 + jj;
        #pragma unroll
        for (int r=0;r<4;r++)
            sc[(quad*4+r)*SROW + o*20 + fr] = acc2[1][jj][r]*0.125f + mv;
    }
    __syncthreads();
    {
        const float* zp = &sc[row*SROW + fr*20];
        #pragma unroll
        for (int jj=0;jj<4;jj++){
            float4 t = *(const float4*)(zp + jj*4);
            z[16+jj*4+0]=t.x; z[16+jj*4+1]=t.y; z[16+jj*4+2]=t.z; z[16+jj*4+3]=t.w;
        }
    }
    // no further sc use -> no barrier needed

    // ---- Row max: depth-5 tree + 4-step intra-quad butterfly --------------
    float tau;
    {
        float red[16];
        #pragma unroll
        for (int i=0;i<16;i++) red[i] = fmaxf(z[i], z[i+16]);
        #pragma unroll
        for (int i=0;i<8;i++)  red[i] = fmaxf(red[i], red[i+8]);
        #pragma unroll
        for (int i=0;i<4;i++)  red[i] = fmaxf(red[i], red[i+4]);
        float mm = fmaxf(fmaxf(red[0],red[1]), fmaxf(red[2],red[3]));
        #pragma unroll
        for (int off=1; off<16; off<<=1) mm = fmaxf(mm, __shfl_xor(mm, off, 64));
        tau = mm - 1.0f;
    }

    // ---- Michelot fixed-point: 4-way partial sums, butterfly --------------
    for (int it=0; it<16; it++){
        float s0=0.f,s1=0.f,s2=0.f,s3=0.f;
        float k0=0.f,k1=0.f,k2=0.f,k3=0.f;
        #pragma unroll
        for (int i=0;i<32;i+=4){
            float z0=z[i], z1=z[i+1], z2=z[i+2], z3=z[i+3];
            if (z0 > tau){ s0 += z0; k0 += 1.f; }
            if (z1 > tau){ s1 += z1; k1 += 1.f; }
            if (z2 > tau){ s2 += z2; k2 += 1.f; }
            if (z3 > tau){ s3 += z3; k3 += 1.f; }
        }
        float ss = (s0+s1)+(s2+s3), kk = (k0+k1)+(k2+k3);
        #pragma unroll
        for (int off=1; off<16; off<<=1){
            ss += __shfl_xor(ss, off, 64);
            kk += __shfl_xor(kk, off, 64);
        }
        float tn = (ss - 1.0f) / kk;
        bool changed = (tn != tau);
        tau = tn;
        if (!__any(changed)) break;
    }

    // ---- Sparse PV: per-quad ballot walk; each support key: 16 lanes x
    // float4 = 256B coalesced V-row read.
    float4 ctx = make_float4(0.f, 0.f, 0.f, 0.f);
    const float* vb = V + hb;
    #pragma unroll
    for (int i=0;i<32;i++){
        float p = z[i] - tau;
        unsigned long long bal = __ballot(p > 0.f);
        unsigned mk = (unsigned)((bal >> (quad*16)) & 0xFFFFull);
        const int base_i = (i < 16) ? i : (240 + i);   // s*16+i  or 256+s*16+(i-16)
        while (mk){
            int s = __ffs(mk) - 1;
            mk &= mk - 1;
            float pv = __shfl(p, quad*16 + s, 64);
            const float4 vv = *(const float4*)(vb + (size_t)(base_i + s*16)*DH_ + fr*4);
            ctx.x += pv * vv.x;
            ctx.y += pv * vv.y;
            ctx.z += pv * vv.z;
            ctx.w += pv * vv.w;
        }
    }

    *(float4*)(out + (size_t)(b*S_ + q0 + row)*D_ + h*DH_ + fr*4) = ctx;
}

// ---------------------------------------------------------------------------
extern "C" void kernel_launch(void* const* d_in, const int* in_sizes, int n_in,
                              void* d_out, int out_size, void* d_ws, size_t ws_size,
                              hipStream_t stream) {
    const float* hs   = (const float*)d_in[0];
    const float* mask = (const float*)d_in[1];
    const float* Wq   = (const float*)d_in[2];
    const float* bq   = (const float*)d_in[3];
    const float* Wk   = (const float*)d_in[4];
    const float* bk   = (const float*)d_in[5];
    const float* Wv   = (const float*)d_in[6];
    const float* bv   = (const float*)d_in[7];
    float* out = (float*)d_out;

    const size_t per = (size_t)BH_ * S_ * DH_;   // 6291456
    char* w = (char*)d_ws;
    float*    vb  = (float*)w;    w += per*4;
    ushort_t* qf  = (ushort_t*)w; w += per*2;
    ushort_t* kf  = (ushort_t*)w; w += per*2;
    ushort_t* Xf  = (ushort_t*)w; w += per*2;
    ushort_t* Wf  = (ushort_t*)w;

    const int ncv = (NX4 + 3*NW4) / 256;   // 6720 blocks, boundaries aligned
    convert_all<<<ncv, 256, 0, stream>>>(hs, Wq, Wk, Wv, Xf, Wf);

    dim3 ggrid(NTOT/BN, MTOT/BM);   // (18, 64)
    gemm_f16<<<ggrid, 256, 0, stream>>>(Xf, Wf, bq, bk, bv, qf, kf, vb);

    attn_mfma<<<BH_*32, 256, 0, stream>>>(qf, kf, vb, mask, out);
}